// Round 1
// baseline (623.278 us; speedup 1.0000x reference)
//
#include <hip/hip_runtime.h>
#include <math.h>

// Problem constants (fixed by the reference): N=8, S=4096, C=2, V=128, K=512
#define N_TOK   32768   // N*S tokens
#define C_CH    2
#define V_DIM   128
#define K_CODES 512

// ---------------------------------------------------------------------------
// Kernel 0: per-row ||e||^2 (C*K = 1024 rows) + zero the histogram.
// One wave per row; coalesced reads; shfl reduction.
// ---------------------------------------------------------------------------
__global__ __launch_bounds__(64) void vq_prep(const float* __restrict__ emb,
                                              float* __restrict__ e_sq,
                                              unsigned int* __restrict__ hist) {
    const int row  = blockIdx.x;      // 0..1023  == c*512 + k
    const int lane = threadIdx.x;     // 0..63
    const float a = emb[(size_t)row * V_DIM + lane];
    const float b = emb[(size_t)row * V_DIM + 64 + lane];
    float s = a * a + b * b;
#pragma unroll
    for (int off = 32; off > 0; off >>= 1) s += __shfl_down(s, off);
    if (lane == 0) {
        e_sq[row] = s;
        if (row < K_CODES) hist[row] = 0u;   // deterministic per-launch init
    }
}

// ---------------------------------------------------------------------------
// Kernel 1: main VQ kernel.
//   grid = (N_TOK/64, C), block = 256 (4 waves).
//   All 4 waves handle the SAME 64 tokens; wave w covers codes
//   k in [w*128, (w+1)*128). x[128] lives in VGPRs. Cross-wave argmin
//   combine in LDS preserves numpy first-min semantics (ascending k,
//   strict '<').
// ---------------------------------------------------------------------------
__global__ __launch_bounds__(256) void vq_main(const float* __restrict__ x0,
                                               const float* __restrict__ emb,
                                               const float* __restrict__ e_sq,
                                               unsigned int* __restrict__ hist,
                                               float* __restrict__ out0,
                                               float* __restrict__ out1,
                                               float* __restrict__ out2) {
    const int c    = blockIdx.y;
    const int b0   = blockIdx.x * 64;          // first token of this block
    const int lane = threadIdx.x & 63;
    const int w    = threadIdx.x >> 6;         // wave id 0..3
    const int b    = b0 + lane;                // this thread's token

    // ---- load x[b,c,:] into 128 VGPRs, accumulate ||x||^2 ----
    const float* xp = x0 + ((size_t)b * C_CH + c) * V_DIM;
    float x[V_DIM];
    float xx = 0.f;
#pragma unroll
    for (int q = 0; q < V_DIM / 4; ++q) {
        float4 t = reinterpret_cast<const float4*>(xp)[q];
        x[4 * q + 0] = t.x; x[4 * q + 1] = t.y;
        x[4 * q + 2] = t.z; x[4 * q + 3] = t.w;
        xx = fmaf(t.x, t.x, xx); xx = fmaf(t.y, t.y, xx);
        xx = fmaf(t.z, t.z, xx); xx = fmaf(t.w, t.w, xx);
    }

    const float* eb  = emb + (size_t)c * K_CODES * V_DIM;
    const float* esq = e_sq + c * K_CODES;

    // ---- argmin over this wave's 128-code range ----
    float best  = INFINITY;
    int   bestk = 0;
    const int kbase = w << 7;  // w*128
    for (int kk = 0; kk < 128; ++kk) {
        const int k = kbase + kk;
        const float4* ep = reinterpret_cast<const float4*>(eb + (size_t)k * V_DIM);
        float a0 = 0.f, a1 = 0.f, a2 = 0.f, a3 = 0.f;
#pragma unroll
        for (int q = 0; q < V_DIM / 4; ++q) {
            float4 e4 = ep[q];
            a0 = fmaf(x[4 * q + 0], e4.x, a0);
            a1 = fmaf(x[4 * q + 1], e4.y, a1);
            a2 = fmaf(x[4 * q + 2], e4.z, a2);
            a3 = fmaf(x[4 * q + 3], e4.w, a3);
        }
        const float dot  = (a0 + a1) + (a2 + a3);
        const float dist = esq[k] - 2.0f * dot;   // ||x||^2 term constant over k
        if (dist < best) { best = dist; bestk = k; }
    }

    // ---- cross-wave argmin combine (ascending wave id => first-min ties) ----
    __shared__ float s_best[4][64];
    __shared__ int   s_bk[4][64];
    __shared__ int   s_idx[64];
    s_best[w][lane] = best;
    s_bk[w][lane]   = bestk;
    __syncthreads();

    if (threadIdx.x < 64) {
        float bb = s_best[0][lane];
        int   bk = s_bk[0][lane];
#pragma unroll
        for (int j = 1; j < 4; ++j) {
            const float d = s_best[j][lane];
            if (d < bb) { bb = d; bk = s_bk[j][lane]; }
        }
        s_idx[lane] = bk;
        // out1 = sum((x-e)^2) = ||x||^2 + (||e||^2 - 2 x.e) ; out2 identical
        // (the (x-x0)^2 term is exactly 0 in the reference).
        const float dtrue = xx + bb;
        const int o = b * C_CH + c;
        out1[o] = dtrue;
        out2[o] = dtrue;
        atomicAdd(&hist[bk], 1u);
    }
    __syncthreads();

    // ---- coalesced out0 gather: out0[b,c,:] = (e[c,idx] - x) + x  ----
    // (mimics the straight-through fp32 rounding of the reference)
    const int v    = threadIdx.x & 127;
    const int half = threadIdx.x >> 7;
    for (int i = half; i < 64; i += 2) {
        const int kk2 = s_idx[i];
        const float ev = eb[(size_t)kk2 * V_DIM + v];
        const size_t o0 = ((size_t)(b0 + i) * C_CH + c) * V_DIM + v;
        const float xv = x0[o0];
        out0[o0] = (ev - xv) + xv;
    }
}

// ---------------------------------------------------------------------------
// Kernel 2: entropy over the 512-bin histogram. prob = hist / 32768 (the
// reference divides by B = N*S, not B*C).
// ---------------------------------------------------------------------------
__global__ __launch_bounds__(512) void vq_entropy(const unsigned int* __restrict__ hist,
                                                  float* __restrict__ ent) {
    const int t = threadIdx.x;       // 0..511
    float v = 0.f;
    const unsigned int h = hist[t];
    if (h > 0u) {
        const float p = (float)h * (1.0f / 32768.0f);
        v = p * logf(p);
    }
#pragma unroll
    for (int off = 32; off > 0; off >>= 1) v += __shfl_down(v, off);
    __shared__ float s[8];
    if ((t & 63) == 0) s[t >> 6] = v;
    __syncthreads();
    if (t == 0) {
        float tot = 0.f;
#pragma unroll
        for (int i = 0; i < 8; ++i) tot += s[i];
        ent[0] = -tot;
    }
}

// ---------------------------------------------------------------------------
extern "C" void kernel_launch(void* const* d_in, const int* in_sizes, int n_in,
                              void* d_out, int out_size, void* d_ws, size_t ws_size,
                              hipStream_t stream) {
    const float* x0  = (const float*)d_in[0];   // (N,S,C,V) fp32
    const float* emb = (const float*)d_in[1];   // (C,K,V)   fp32

    float*        e_sq = (float*)d_ws;                            // 1024 floats
    unsigned int* hist = (unsigned int*)((char*)d_ws + 4096);     // 512 uints

    float* out0 = (float*)d_out;                                  // 8388608
    float* out1 = out0 + (size_t)N_TOK * C_CH * V_DIM;            // 65536
    float* out2 = out1 + (size_t)N_TOK * C_CH;                    // 65536
    float* ent  = out2 + (size_t)N_TOK * C_CH;                    // 1

    vq_prep<<<C_CH * K_CODES, 64, 0, stream>>>(emb, e_sq, hist);
    vq_main<<<dim3(N_TOK / 64, C_CH), 256, 0, stream>>>(x0, emb, e_sq, hist,
                                                        out0, out1, out2);
    vq_entropy<<<1, K_CODES, 0, stream>>>(hist, ent);
}

// Round 2
// 197.763 us; speedup vs baseline: 3.1516x; 3.1516x over previous
//
#include <hip/hip_runtime.h>
#include <math.h>

// Problem constants (fixed by the reference): N=8, S=4096, C=2, V=128, K=512
#define N_TOK   32768   // N*S tokens
#define C_CH    2
#define V_DIM   128
#define K_CODES 512

typedef __attribute__((address_space(1))) const unsigned char* gas_t;
typedef __attribute__((address_space(3))) unsigned char* las_t;

// ---------------------------------------------------------------------------
// Kernel 0: per-row ||e||^2 (C*K = 1024 rows) + zero the histogram.
// ---------------------------------------------------------------------------
__global__ __launch_bounds__(64) void vq_prep(const float* __restrict__ emb,
                                              float* __restrict__ e_sq,
                                              unsigned int* __restrict__ hist) {
    const int row  = blockIdx.x;      // 0..1023  == c*512 + k
    const int lane = threadIdx.x;     // 0..63
    const float a = emb[(size_t)row * V_DIM + lane];
    const float b = emb[(size_t)row * V_DIM + 64 + lane];
    float s = a * a + b * b;
#pragma unroll
    for (int off = 32; off > 0; off >>= 1) s += __shfl_down(s, off);
    if (lane == 0) {
        e_sq[row] = s;
        if (row < K_CODES) hist[row] = 0u;
    }
}

// ---------------------------------------------------------------------------
// Kernel 1: main VQ kernel — register-tiled LDS GEMM + fused argmin.
//   grid = (N_TOK/64, C), block = 256 (4 waves).
//   Wave w owns tokens w*16..w*16+15; thread (r=lane>>4, tn=lane&15)
//   computes acc[4 tokens][8 codes]; codes = ct*128 + tn + 16*j.
//   e chunk LDS layout: [code][8 slots of 16B], slot = v4 ^ (code&7)
//   (XOR swizzle -> 2-way max on reads; staged with pre-swizzled
//   global addresses through global_load_lds -> conflict-free writes).
//   x tile LDS: padded rows of 132 floats (2-way max on reads).
// ---------------------------------------------------------------------------
__global__ __launch_bounds__(256, 3) void vq_main(const float* __restrict__ x0,
                                                  const float* __restrict__ emb,
                                                  const float* __restrict__ e_sq,
                                                  unsigned int* __restrict__ hist,
                                                  float* __restrict__ out0,
                                                  float* __restrict__ out1,
                                                  float* __restrict__ out2) {
    __shared__ float xs[64 * 132];     // 33792 B padded x tile
    __shared__ float es[128 * 32];     // 16384 B e chunk (swizzled slots)
    __shared__ float esq_s[K_CODES];   // 2048 B
    __shared__ float xx_s[64];
    __shared__ int   idx_s[64];

    const int c   = blockIdx.y;
    const int gt0 = blockIdx.x * 64;     // first token of this block
    const int t    = threadIdx.x;
    const int lane = t & 63;
    const int w    = t >> 6;             // wave 0..3
    const int tn   = lane & 15;          // code group 0..15
    const int r    = lane >> 4;          // token subgroup 0..3
    const int s7   = tn & 7;

    const float* ec = emb + (size_t)c * K_CODES * V_DIM;

    // ---- stage x tile (padded) + per-token ||x||^2 ----
#pragma unroll
    for (int p = 0; p < 8; ++p) {
        const int bt  = p * 8 + (t >> 5);   // block token 0..63
        const int v4f = t & 31;
        const float4 xv = *reinterpret_cast<const float4*>(
            x0 + ((size_t)(gt0 + bt) * C_CH + c) * V_DIM + v4f * 4);
        *reinterpret_cast<float4*>(&xs[bt * 132 + v4f * 4]) = xv;
        float part = xv.x * xv.x + xv.y * xv.y + xv.z * xv.z + xv.w * xv.w;
#pragma unroll
        for (int m = 16; m > 0; m >>= 1) part += __shfl_xor(part, m);
        if (v4f == 0) xx_s[bt] = part;
    }
    // ---- stage e_sq for this channel ----
    esq_s[t]       = e_sq[c * K_CODES + t];
    esq_s[t + 256] = e_sq[c * K_CODES + t + 256];

    unsigned long long best[4] = {~0ull, ~0ull, ~0ull, ~0ull};

    for (int ct = 0; ct < 4; ++ct) {           // code tiles of 128
        float acc[4][8];
#pragma unroll
        for (int i = 0; i < 4; ++i)
#pragma unroll
            for (int j = 0; j < 8; ++j) acc[i][j] = 0.f;

        for (int vc = 0; vc < 4; ++vc) {       // v chunks of 32
            __syncthreads();                   // protect es from prior reads
            // stage e chunk: 4 x 1KB regions per wave, pre-swizzled source
#pragma unroll
            for (int q = 0; q < 4; ++q) {
                const int c0   = (w * 4 + q) * 8;            // local code base
                const int code = ct * 128 + c0 + (lane >> 3);
                const int v4g  = (lane & 7) ^ (code & 7);
                const float* gsrc = ec + (size_t)code * V_DIM + vc * 32 + v4g * 4;
                __builtin_amdgcn_global_load_lds(
                    (gas_t)(const unsigned char*)gsrc,
                    (las_t)(unsigned char*)&es[c0 * 32], 16, 0, 0);
            }
            __syncthreads();                   // drains vmcnt, es ready

#pragma unroll
            for (int v4 = 0; v4 < 8; ++v4) {
                float4 xf[4];
#pragma unroll
                for (int i = 0; i < 4; ++i)
                    xf[i] = *reinterpret_cast<const float4*>(
                        &xs[(w * 16 + 4 * r + i) * 132 + (vc * 8 + v4) * 4]);
#pragma unroll
                for (int j = 0; j < 8; ++j) {
                    const float4 ef = *reinterpret_cast<const float4*>(
                        &es[(tn + 16 * j) * 32 + ((v4 ^ s7) * 4)]);
#pragma unroll
                    for (int i = 0; i < 4; ++i) {
                        acc[i][j] = fmaf(xf[i].x, ef.x, acc[i][j]);
                        acc[i][j] = fmaf(xf[i].y, ef.y, acc[i][j]);
                        acc[i][j] = fmaf(xf[i].z, ef.z, acc[i][j]);
                        acc[i][j] = fmaf(xf[i].w, ef.w, acc[i][j]);
                    }
                }
            }
        }

        // fold this code tile into the running argmin (numpy first-min ties)
#pragma unroll
        for (int i = 0; i < 4; ++i) {
#pragma unroll
            for (int j = 0; j < 8; ++j) {
                const int k = ct * 128 + tn + 16 * j;
                const float d = esq_s[k] - 2.0f * acc[i][j];
                unsigned u = __float_as_uint(d);
                u = ((int)u < 0) ? ~u : (u | 0x80000000u);  // monotone map
                const unsigned long long pk =
                    ((unsigned long long)u << 32) | (unsigned)k;
                if (pk < best[i]) best[i] = pk;
            }
        }
    }

    // ---- cross-lane argmin over the 16 code-groups sharing each token ----
#pragma unroll
    for (int i = 0; i < 4; ++i) {
        unsigned long long b = best[i];
#pragma unroll
        for (int m = 1; m <= 8; m <<= 1) {
            const unsigned long long o = __shfl_xor(b, m);
            if (o < b) b = o;
        }
        best[i] = b;
    }
    if (tn == 0) {
#pragma unroll
        for (int i = 0; i < 4; ++i) {
            const int bt = w * 16 + 4 * r + i;
            const unsigned long long b = best[i];
            const int k = (int)(b & 0xFFFFFFFFu);
            const unsigned u = (unsigned)(b >> 32);
            const float d = __uint_as_float((u & 0x80000000u) ? (u & 0x7FFFFFFFu)
                                                              : ~u);
            const float o12 = xx_s[bt] + d;   // ||x||^2 + (||e||^2 - 2 x.e)
            const size_t oi = (size_t)(gt0 + bt) * C_CH + c;
            out1[oi] = o12;
            out2[oi] = o12;
            idx_s[bt] = k;
            atomicAdd(&hist[k], 1u);
        }
    }
    __syncthreads();

    // ---- coalesced out0 gather: out0[b,c,:] = (e[c,idx] - x) + x ----
#pragma unroll
    for (int p = 0; p < 8; ++p) {
        const int bt  = p * 8 + (t >> 5);
        const int v4f = t & 31;
        const int k   = idx_s[bt];
        const float4 ev = *reinterpret_cast<const float4*>(
            ec + (size_t)k * V_DIM + v4f * 4);
        const float4 xv = *reinterpret_cast<const float4*>(&xs[bt * 132 + v4f * 4]);
        float4 ov;
        ov.x = (ev.x - xv.x) + xv.x;
        ov.y = (ev.y - xv.y) + xv.y;
        ov.z = (ev.z - xv.z) + xv.z;
        ov.w = (ev.w - xv.w) + xv.w;
        *reinterpret_cast<float4*>(
            out0 + ((size_t)(gt0 + bt) * C_CH + c) * V_DIM + v4f * 4) = ov;
    }
}

// ---------------------------------------------------------------------------
// Kernel 2: entropy over the 512-bin histogram (prob = hist / 32768).
// ---------------------------------------------------------------------------
__global__ __launch_bounds__(512) void vq_entropy(const unsigned int* __restrict__ hist,
                                                  float* __restrict__ ent) {
    const int t = threadIdx.x;       // 0..511
    float v = 0.f;
    const unsigned int h = hist[t];
    if (h > 0u) {
        const float p = (float)h * (1.0f / 32768.0f);
        v = p * logf(p);
    }
#pragma unroll
    for (int off = 32; off > 0; off >>= 1) v += __shfl_down(v, off);
    __shared__ float s[8];
    if ((t & 63) == 0) s[t >> 6] = v;
    __syncthreads();
    if (t == 0) {
        float tot = 0.f;
#pragma unroll
        for (int i = 0; i < 8; ++i) tot += s[i];
        ent[0] = -tot;
    }
}

// ---------------------------------------------------------------------------
extern "C" void kernel_launch(void* const* d_in, const int* in_sizes, int n_in,
                              void* d_out, int out_size, void* d_ws, size_t ws_size,
                              hipStream_t stream) {
    const float* x0  = (const float*)d_in[0];   // (N,S,C,V) fp32
    const float* emb = (const float*)d_in[1];   // (C,K,V)   fp32

    float*        e_sq = (float*)d_ws;                            // 1024 floats
    unsigned int* hist = (unsigned int*)((char*)d_ws + 4096);     // 512 uints

    float* out0 = (float*)d_out;                                  // 8388608
    float* out1 = out0 + (size_t)N_TOK * C_CH * V_DIM;            // 65536
    float* out2 = out1 + (size_t)N_TOK * C_CH;                    // 65536
    float* ent  = out2 + (size_t)N_TOK * C_CH;                    // 1

    vq_prep<<<C_CH * K_CODES, 64, 0, stream>>>(emb, e_sq, hist);
    vq_main<<<dim3(N_TOK / 64, C_CH), 256, 0, stream>>>(x0, emb, e_sq, hist,
                                                        out0, out1, out2);
    vq_entropy<<<1, K_CODES, 0, stream>>>(hist, ent);
}

// Round 3
// 76.373 us; speedup vs baseline: 8.1609x; 2.5894x over previous
//
#include <hip/hip_runtime.h>
#include <math.h>

// Problem constants: N=8, S=4096, C=2, V=128, K=512
#define N_TOK   32768
#define C_CH    2
#define V_DIM   128
#define K_CODES 512
#define TPB     128          // tokens per block
#define BAND    4.0e-3f      // >= 2*beta, beta = rigorous bf16-screen error bound

typedef short     bf16v8 __attribute__((ext_vector_type(8)));   // 8 bf16 = 4 VGPR
typedef float     f32x4  __attribute__((ext_vector_type(4)));
typedef unsigned  u32x4  __attribute__((ext_vector_type(4)));
typedef __attribute__((address_space(1))) const unsigned char* gas_t;
typedef __attribute__((address_space(3))) unsigned char* las_t;

// round-to-nearest-even fp32 -> bf16 (keeps screen error <= half-ulp)
__device__ inline unsigned f2bf(float f) {
    unsigned u = __float_as_uint(f);
    return (u + 0x7FFFu + ((u >> 16) & 1u)) >> 16;
}

// ---------------------------------------------------------------------------
// Kernel 0: per-row ||e||^2 (fp32), zero hist, and build the pre-swizzled
// bf16 e-image: img[(row*16 + sp)*16B] = e_row[slot = sp ^ (row&7)] (8 bf16).
// LDS-linear global_load_lds of this image yields an XOR-swizzled LDS tile.
// ---------------------------------------------------------------------------
__global__ __launch_bounds__(64) void vq_prep(const float* __restrict__ emb,
                                              float* __restrict__ e_sq,
                                              unsigned int* __restrict__ hist,
                                              unsigned char* __restrict__ img) {
    const int row  = blockIdx.x;          // c*512 + k
    const int k    = row & (K_CODES - 1);
    const int lane = threadIdx.x;
    const float a = emb[(size_t)row * V_DIM + lane];
    const float b = emb[(size_t)row * V_DIM + 64 + lane];
    float s = a * a + b * b;
#pragma unroll
    for (int off = 32; off; off >>= 1) s += __shfl_down(s, off);
    if (lane == 0) {
        e_sq[row] = s;
        if (row < K_CODES) hist[row] = 0u;
    }
    if (lane < 16) {
        const int sp = lane;               // physical slot in image/LDS
        const int sl = sp ^ (k & 7);       // logical slot (8 bf16 = 16 elems.. 8 floats)
        const float* src = emb + (size_t)row * V_DIM + sl * 8;
        u32x4 val;
#pragma unroll
        for (int q = 0; q < 4; ++q)
            val[q] = f2bf(src[2 * q]) | (f2bf(src[2 * q + 1]) << 16);
        *reinterpret_cast<u32x4*>(img + ((size_t)row * 16 + sp) * 16) = val;
    }
}

// ---------------------------------------------------------------------------
// Kernel 1: main VQ kernel.
//   grid (256, 2), block 256 (4 waves). Wave w owns tokens w*32..w*32+31
//   (two 16-row M-tiles). Sweep 1: bf16 MFMA over all 512 codes (4 LDS
//   quarters), fold running min of d~ = esq - 2*dot per token. Cross-lane
//   reduce -> m~. Sweep 2: recompute (bit-identical), collect candidates
//   d~ <= m~ + BAND. Exact fp32 phase decides argmin among candidates
//   (packed u64 keeps numpy first-min tie semantics). Epilogue: out1/out2,
//   hist, coalesced out0 gather from fp32 emb.
// ---------------------------------------------------------------------------
__global__ __launch_bounds__(256, 2) void vq_main(const float* __restrict__ x0,
                                                  const float* __restrict__ emb,
                                                  const float* __restrict__ e_sq,
                                                  const unsigned char* __restrict__ img,
                                                  unsigned int* __restrict__ hist,
                                                  float* __restrict__ out0,
                                                  float* __restrict__ out1,
                                                  float* __restrict__ out2) {
    __shared__ __align__(16) unsigned char xs[TPB * 256];   // 32 KB x bf16 (swizzled)
    __shared__ __align__(16) unsigned char es[128 * 256];   // 32 KB e quarter (swizzled)
    __shared__ float esq_s[K_CODES];
    __shared__ float xx_s[TPB];
    __shared__ unsigned long long best_s[TPB];
    __shared__ unsigned int cand[1024];
    __shared__ int cand_n;

    const int c    = blockIdx.y;
    const int gt0  = blockIdx.x * TPB;
    const int t    = threadIdx.x;
    const int lane = t & 63;
    const int w    = t >> 6;
    const int l15  = lane & 15;
    const int l4   = lane >> 4;

    if (t < TPB) best_s[t] = ~0ull;
    if (t == 0) cand_n = 0;
    esq_s[t]       = e_sq[c * K_CODES + t];
    esq_s[t + 256] = e_sq[c * K_CODES + t + 256];

    // ---- stage x: fp32 -> bf16 (RNE) swizzled tile + ||x||^2 ----
    {
        const int row  = t >> 1;          // 0..127
        const int half = t & 1;
        const float* xp = x0 + ((size_t)(gt0 + row) * C_CH + c) * V_DIM + half * 64;
        float xxp = 0.f;
#pragma unroll
        for (int q = 0; q < 8; ++q) {
            f32x4 p0 = *reinterpret_cast<const f32x4*>(xp + q * 8);
            f32x4 p1 = *reinterpret_cast<const f32x4*>(xp + q * 8 + 4);
            xxp = fmaf(p0[0], p0[0], xxp); xxp = fmaf(p0[1], p0[1], xxp);
            xxp = fmaf(p0[2], p0[2], xxp); xxp = fmaf(p0[3], p0[3], xxp);
            xxp = fmaf(p1[0], p1[0], xxp); xxp = fmaf(p1[1], p1[1], xxp);
            xxp = fmaf(p1[2], p1[2], xxp); xxp = fmaf(p1[3], p1[3], xxp);
            u32x4 val;
            val[0] = f2bf(p0[0]) | (f2bf(p0[1]) << 16);
            val[1] = f2bf(p0[2]) | (f2bf(p0[3]) << 16);
            val[2] = f2bf(p1[0]) | (f2bf(p1[1]) << 16);
            val[3] = f2bf(p1[2]) | (f2bf(p1[3]) << 16);
            const int sp = (half * 8 + q) ^ (row & 7);
            *reinterpret_cast<u32x4*>(xs + (size_t)row * 256 + sp * 16) = val;
        }
        xxp += __shfl_xor(xxp, 1);
        if (half == 0) xx_s[row] = xxp;
    }
    __syncthreads();

    // ---- A fragments: 2 M-tiles x 4 k-chunks, loaded once ----
    u32x4 Af[2][4];
#pragma unroll
    for (int m = 0; m < 2; ++m)
#pragma unroll
        for (int kk = 0; kk < 4; ++kk) {
            const int row = w * 32 + m * 16 + l15;
            const int sp  = (kk * 4 + l4) ^ (row & 7);
            Af[m][kk] = *reinterpret_cast<const u32x4*>(xs + (size_t)row * 256 + sp * 16);
        }

    float rmin[2][4];
#pragma unroll
    for (int m = 0; m < 2; ++m)
#pragma unroll
        for (int r = 0; r < 4; ++r) rmin[m][r] = INFINITY;

    // ---- two sweeps over the 4 e-quarters ----
    for (int sweep = 0; sweep < 2; ++sweep) {
        for (int Q = 0; Q < 4; ++Q) {
            __syncthreads();   // prior readers of es done
            const unsigned char* src = img + (size_t)(c * K_CODES + Q * 128) * 256;
#pragma unroll
            for (int i = 0; i < 8; ++i) {
                const int chunk = i * 256 + w * 64;   // wave-uniform LDS base
                __builtin_amdgcn_global_load_lds(
                    (gas_t)(src + (size_t)(chunk + lane) * 16),
                    (las_t)(es + (size_t)chunk * 16), 16, 0, 0);
            }
            __syncthreads();   // vmcnt drained; es ready

            for (int j = 0; j < 8; ++j) {
                f32x4 acc0 = {0.f, 0.f, 0.f, 0.f};
                f32x4 acc1 = {0.f, 0.f, 0.f, 0.f};
                const int code = j * 16 + l15;        // local code in quarter
#pragma unroll
                for (int kk = 0; kk < 4; ++kk) {
                    const int sp = (kk * 4 + l4) ^ (code & 7);
                    bf16v8 B = __builtin_bit_cast(bf16v8,
                        *reinterpret_cast<const u32x4*>(es + (size_t)code * 256 + sp * 16));
                    acc0 = __builtin_amdgcn_mfma_f32_16x16x32_bf16(
                        __builtin_bit_cast(bf16v8, Af[0][kk]), B, acc0, 0, 0, 0);
                    acc1 = __builtin_amdgcn_mfma_f32_16x16x32_bf16(
                        __builtin_bit_cast(bf16v8, Af[1][kk]), B, acc1, 0, 0, 0);
                }
                const int   kglob = Q * 128 + code;
                const float esv   = esq_s[kglob];
                if (sweep == 0) {
#pragma unroll
                    for (int r = 0; r < 4; ++r) {
                        rmin[0][r] = fminf(rmin[0][r], fmaf(-2.f, acc0[r], esv));
                        rmin[1][r] = fminf(rmin[1][r], fmaf(-2.f, acc1[r], esv));
                    }
                } else {
#pragma unroll
                    for (int m = 0; m < 2; ++m)
#pragma unroll
                        for (int r = 0; r < 4; ++r) {
                            const float d = fmaf(-2.f, (m ? acc1[r] : acc0[r]), esv);
                            if (d <= rmin[m][r] + BAND) {
                                const int tok = w * 32 + m * 16 + l4 * 4 + r;
                                const int pos = atomicAdd(&cand_n, 1);
                                if (pos < 1024)
                                    cand[pos] = ((unsigned)tok << 9) | (unsigned)kglob;
                            }
                        }
                }
            }
        }
        if (sweep == 0) {
            // cross-lane min over the 16 lanes sharing each token
#pragma unroll
            for (int m = 0; m < 2; ++m)
#pragma unroll
                for (int r = 0; r < 4; ++r) {
                    float v = rmin[m][r];
#pragma unroll
                    for (int s = 1; s < 16; s <<= 1) v = fminf(v, __shfl_xor(v, s));
                    rmin[m][r] = v;
                }
        }
    }

    // ---- exact fp32 phase over collected candidates ----
    __syncthreads();
    const int n = cand_n < 1024 ? cand_n : 1024;
    for (int i = t; i < n; i += 256) {
        const unsigned key = cand[i];
        const int tok = key >> 9;
        const int k   = key & (K_CODES - 1);
        const float* xg = x0 + ((size_t)(gt0 + tok) * C_CH + c) * V_DIM;
        const float* eg = emb + ((size_t)c * K_CODES + k) * V_DIM;
        float a0 = 0.f, a1 = 0.f, a2 = 0.f, a3 = 0.f;
#pragma unroll
        for (int q = 0; q < 32; ++q) {
            f32x4 xv = *reinterpret_cast<const f32x4*>(xg + q * 4);
            f32x4 ev = *reinterpret_cast<const f32x4*>(eg + q * 4);
            a0 = fmaf(xv[0], ev[0], a0);
            a1 = fmaf(xv[1], ev[1], a1);
            a2 = fmaf(xv[2], ev[2], a2);
            a3 = fmaf(xv[3], ev[3], a3);
        }
        const float dot = (a0 + a1) + (a2 + a3);
        const float d   = fmaf(-2.f, dot, esq_s[k]);
        unsigned u = __float_as_uint(d);
        u = ((int)u < 0) ? ~u : (u | 0x80000000u);   // monotone map
        atomicMin(&best_s[tok], ((unsigned long long)u << 32) | (unsigned)k);
    }
    __syncthreads();

    // ---- out1/out2/hist ----
    if (t < TPB) {
        const unsigned long long b = best_s[t];
        const int k = (int)(b & (unsigned)(K_CODES - 1));
        const unsigned u = (unsigned)(b >> 32);
        const float d = __uint_as_float((u & 0x80000000u) ? (u & 0x7FFFFFFFu) : ~u);
        const float o12 = xx_s[t] + d;
        const size_t oi = (size_t)(gt0 + t) * C_CH + c;
        out1[oi] = o12;
        out2[oi] = o12;
        atomicAdd(&hist[k], 1u);
    }

    // ---- coalesced out0 gather: (e - x) + x in fp32 ----
#pragma unroll
    for (int i = 0; i < 16; ++i) {
        const int tok = i * 8 + (t >> 5);
        const int v4  = t & 31;
        const int k   = (int)(best_s[tok] & (unsigned long long)(K_CODES - 1));
        const float* eg = emb + ((size_t)c * K_CODES + k) * V_DIM + v4 * 4;
        const float* xg = x0 + ((size_t)(gt0 + tok) * C_CH + c) * V_DIM + v4 * 4;
        f32x4 ev = *reinterpret_cast<const f32x4*>(eg);
        f32x4 xv = *reinterpret_cast<const f32x4*>(xg);
        f32x4 ov;
#pragma unroll
        for (int z = 0; z < 4; ++z) ov[z] = (ev[z] - xv[z]) + xv[z];
        *reinterpret_cast<f32x4*>(out0 + ((size_t)(gt0 + tok) * C_CH + c) * V_DIM + v4 * 4) = ov;
    }
}

// ---------------------------------------------------------------------------
// Kernel 2: entropy over the 512-bin histogram (prob = hist / 32768).
// ---------------------------------------------------------------------------
__global__ __launch_bounds__(512) void vq_entropy(const unsigned int* __restrict__ hist,
                                                  float* __restrict__ ent) {
    const int t = threadIdx.x;
    float v = 0.f;
    const unsigned int h = hist[t];
    if (h > 0u) {
        const float p = (float)h * (1.0f / 32768.0f);
        v = p * logf(p);
    }
#pragma unroll
    for (int off = 32; off; off >>= 1) v += __shfl_down(v, off);
    __shared__ float s[8];
    if ((t & 63) == 0) s[t >> 6] = v;
    __syncthreads();
    if (t == 0) {
        float tot = 0.f;
#pragma unroll
        for (int i = 0; i < 8; ++i) tot += s[i];
        ent[0] = -tot;
    }
}

// ---------------------------------------------------------------------------
extern "C" void kernel_launch(void* const* d_in, const int* in_sizes, int n_in,
                              void* d_out, int out_size, void* d_ws, size_t ws_size,
                              hipStream_t stream) {
    const float* x0  = (const float*)d_in[0];   // (N,S,C,V) fp32
    const float* emb = (const float*)d_in[1];   // (C,K,V)   fp32

    float*         e_sq = (float*)d_ws;                          // 1024 f32
    unsigned int*  hist = (unsigned int*)((char*)d_ws + 4096);   // 512 u32
    unsigned char* img  = (unsigned char*)d_ws + 8192;           // 256 KB bf16 image

    float* out0 = (float*)d_out;
    float* out1 = out0 + (size_t)N_TOK * C_CH * V_DIM;
    float* out2 = out1 + (size_t)N_TOK * C_CH;
    float* ent  = out2 + (size_t)N_TOK * C_CH;

    vq_prep<<<C_CH * K_CODES, 64, 0, stream>>>(emb, e_sq, hist, img);
    vq_main<<<dim3(N_TOK / TPB, C_CH), 256, 0, stream>>>(x0, emb, e_sq, img, hist,
                                                         out0, out1, out2);
    vq_entropy<<<1, K_CODES, 0, stream>>>(hist, ent);
}